// Round 4
// baseline (885.748 us; speedup 1.0000x reference)
//
#include <hip/hip_runtime.h>

#define LOG2E 1.44269504088896340736f

// Broadcast lane `lane`'s value to all lanes (wave-uniform SGPR result).
__device__ __forceinline__ float rl(float v, int lane) {
    return __int_as_float(__builtin_amdgcn_readlane(__float_as_int(v), lane));
}

// One wave per TWO sequences (A, B interleaved). Lane l owns gate rows r0=l
// (i for l<32 / f for l>=32) and r1=l+64 (g / o) — shared by both sequences,
// so the 64 resident weights are paid once. The two sequences' dependence
// chains are independent: while A's readlane->fma->exp2->rcp chain stalls,
// B issues — this hides the ~190 cyc/step of exposed latency measured at
// round 2's 1-chain/wave (VALUBusy 69%).
//
// Round-3 lesson baked in: NO per-step LDS reads for weights/h — the DS pipe
// is shared per-CU and serializes across waves (measured 780 cyc/step).
// LDS use is only: 2 fire-and-forget psum writes/step + amortized chunk
// reduction. h broadcast is pure readlane.
//
// Issue trims vs round 2: weights/biases prescaled by -log2e (sigmoid rows)
// / -2log2e (tanh rows) so activations need no mul; gate-select cndmasks
// dropped — lanes>=32 compute bounded garbage c',h' (c' = i*c'+f*o stays in
// (0, ~1e3); exp2 underflows to 0 -> tanh -> 1; woutv=0 kills its psum term;
// readlanes only read lanes<32, so garbage never propagates).
__global__ __launch_bounds__(64, 1) void lstm_seq2_kernel(
    const float* __restrict__ x,      // [B, T]
    const float* __restrict__ W_ih,   // [128]
    const float* __restrict__ W_hh,   // [128, 32]
    const float* __restrict__ b_ih,   // [128]
    const float* __restrict__ b_hh,   // [128]
    const float* __restrict__ W_out,  // [32]
    const float* __restrict__ b_out,  // [1]
    float* __restrict__ out,          // [B, T]
    int T)
{
    __shared__ float psumA[64 * 68];  // [step][lane] output partials, seq A
    __shared__ float psumB[64 * 68];  // row stride 68 floats: 16B-aligned

    const int b = blockIdx.x;
    const int l = threadIdx.x;        // 0..63
    const int r0 = l;                 // i (l<32) / f (l>=32): sigmoid rows
    const int r1 = l + 64;            // g (l<32) / o (l>=32)
    const bool lo = (l < 32);

    const float sc0 = -LOG2E;                           // sigmoid prescale
    const float sc1 = lo ? (-2.0f * LOG2E) : (-LOG2E);  // tanh / sigmoid

    // Preload both prescaled W_hh rows into registers (one-time).
    float w0[32], w1[32];
#pragma unroll
    for (int k = 0; k < 32; k += 4) {
        float4 a = *(const float4*)(W_hh + r0 * 32 + k);
        w0[k] = a.x * sc0; w0[k+1] = a.y * sc0; w0[k+2] = a.z * sc0; w0[k+3] = a.w * sc0;
        float4 g = *(const float4*)(W_hh + r1 * 32 + k);
        w1[k] = g.x * sc1; w1[k+1] = g.y * sc1; w1[k+2] = g.z * sc1; w1[k+3] = g.w * sc1;
    }
    // Opaque to the compiler: prevents rematerializing the loads in-loop.
#pragma unroll
    for (int k = 0; k < 32; ++k) {
        asm volatile("" : "+v"(w0[k]));
        asm volatile("" : "+v"(w1[k]));
    }

    const float wih0  = W_ih[r0] * sc0;
    const float wih1  = W_ih[r1] * sc1;
    const float bias0 = (b_ih[r0] + b_hh[r0]) * sc0;
    const float bias1 = (b_ih[r1] + b_hh[r1]) * sc1;
    const float A1 = lo ? 2.0f : 1.0f;   // tanh = 2*rcp(1+e2)-1 ; sigmoid = rcp(1+e2)
    const float B1 = lo ? -1.0f : 0.0f;
    const float woutv = lo ? W_out[l] : 0.0f;  // upper half: garbage h -> weight 0
    const float bout  = b_out[0];

    float hA = 0.0f, cA = 0.0f, hB = 0.0f, cB = 0.0f;

    const float* xpA = x + (size_t)(2 * b) * T;
    const float* xpB = xpA + T;
    float*       opA = out + (size_t)(2 * b) * T;
    float*       opB = opA + T;

    float xvA = xpA[l];               // chunk 0 inputs, coalesced
    float xvB = xpB[l];

    for (int t0 = 0; t0 < T; t0 += 64) {
        const int tn = (t0 + 64 < T) ? (t0 + 64) : t0;
        float xnA = xpA[tn + l];      // prefetch next chunk (off critical path)
        float xnB = xpB[tn + l];

#pragma unroll 4
        for (int tu = 0; tu < 64; ++tu) {
            const float xtA = rl(xvA, tu);
            const float xtB = rl(xvB, tu);

            // Gate pre-activations (prescaled): 2 chains/row/seq for ILP.
            float a0A = fmaf(wih0, xtA, bias0), a1A = fmaf(wih1, xtA, bias1);
            float a0B = fmaf(wih0, xtB, bias0), a1B = fmaf(wih1, xtB, bias1);
            float b0A = 0.0f, b1A = 0.0f, b0B = 0.0f, b1B = 0.0f;
#pragma unroll
            for (int k = 0; k < 32; k += 2) {
                const float hk0A = rl(hA, k);
                const float hk1A = rl(hA, k + 1);
                const float hk0B = rl(hB, k);
                const float hk1B = rl(hB, k + 1);
                a0A = fmaf(w0[k],     hk0A, a0A);
                b0A = fmaf(w0[k + 1], hk1A, b0A);
                a1A = fmaf(w1[k],     hk0A, a1A);
                b1A = fmaf(w1[k + 1], hk1A, b1A);
                a0B = fmaf(w0[k],     hk0B, a0B);
                b0B = fmaf(w0[k + 1], hk1B, b0B);
                a1B = fmaf(w1[k],     hk0B, a1B);
                b1B = fmaf(w1[k + 1], hk1B, b1B);
            }
            const float G0A = a0A + b0A, G1A = a1A + b1A;
            const float G0B = a0B + b0B, G1B = a1B + b1B;

            // Activations: exp2 + add + rcp (prescale already applied).
            const float s0A = __builtin_amdgcn_rcpf(1.0f + __builtin_amdgcn_exp2f(G0A));
            const float s1A = fmaf(A1, __builtin_amdgcn_rcpf(1.0f + __builtin_amdgcn_exp2f(G1A)), B1);
            const float s0B = __builtin_amdgcn_rcpf(1.0f + __builtin_amdgcn_exp2f(G0B));
            const float s1B = fmaf(A1, __builtin_amdgcn_rcpf(1.0f + __builtin_amdgcn_exp2f(G1B)), B1);

            // Exchange across half-wave: lanes<32 receive (f,o); no cndmask —
            // lanes>=32 compute bounded garbage (see header comment).
            const float o0A = __shfl_xor(s0A, 32, 64);
            const float o1A = __shfl_xor(s1A, 32, 64);
            const float o0B = __shfl_xor(s0B, 32, 64);
            const float o1B = __shfl_xor(s1B, 32, 64);

            cA = fmaf(o0A, cA, s0A * s1A);   // f*c + i*g   (lanes<32)
            cB = fmaf(o0B, cB, s0B * s1B);
            const float tcA = fmaf(2.0f, __builtin_amdgcn_rcpf(
                1.0f + __builtin_amdgcn_exp2f(-2.0f * LOG2E * cA)), -1.0f);
            const float tcB = fmaf(2.0f, __builtin_amdgcn_rcpf(
                1.0f + __builtin_amdgcn_exp2f(-2.0f * LOG2E * cB)), -1.0f);
            hA = o1A * tcA;                  // o * tanh(c) (lanes<32)
            hB = o1B * tcB;

            psumA[tu * 68 + l] = hA * woutv; // fire-and-forget DS writes
            psumB[tu * 68 + l] = hB * woutv;
        }

        __syncthreads();  // single wave: cheap waitcnt; drain psum writes

        // Lane j reduces psum row j -> out[t0+j], both sequences.
        {
            const float4* rowA = (const float4*)(psumA + l * 68);
            const float4* rowB = (const float4*)(psumB + l * 68);
            float4 sA = rowA[0], sB = rowB[0];
#pragma unroll
            for (int m = 1; m < 16; ++m) {
                float4 vA = rowA[m], vB = rowB[m];
                sA.x += vA.x; sA.y += vA.y; sA.z += vA.z; sA.w += vA.w;
                sB.x += vB.x; sB.y += vB.y; sB.z += vB.z; sB.w += vB.w;
            }
            opA[t0 + l] = (sA.x + sA.y) + (sA.z + sA.w) + bout;
            opB[t0 + l] = (sB.x + sB.y) + (sB.z + sB.w) + bout;
        }

        __syncthreads();  // next chunk overwrites psum
        xvA = xnA;
        xvB = xnB;
    }
}

extern "C" void kernel_launch(void* const* d_in, const int* in_sizes, int n_in,
                              void* d_out, int out_size, void* d_ws, size_t ws_size,
                              hipStream_t stream) {
    const float* x     = (const float*)d_in[0];   // [1024, 2048, 1]
    const float* W_ih  = (const float*)d_in[1];   // [128, 1]
    const float* W_hh  = (const float*)d_in[2];   // [128, 32]
    const float* b_ih  = (const float*)d_in[3];   // [128]
    const float* b_hh  = (const float*)d_in[4];   // [128]
    const float* W_out = (const float*)d_in[5];   // [1, 32]
    const float* b_out = (const float*)d_in[6];   // [1]
    float* out = (float*)d_out;                   // [1024, 2048, 1]

    const int B = 1024;
    const int T = 2048;
    lstm_seq2_kernel<<<B / 2, 64, 0, stream>>>(x, W_ih, W_hh, b_ih, b_hh,
                                               W_out, b_out, out, T);
}

// Round 5
// 525.699 us; speedup vs baseline: 1.6849x; 1.6849x over previous
//
#include <hip/hip_runtime.h>

#define LOG2E 1.44269504088896340736f

typedef _Float16 half2_t __attribute__((ext_vector_type(2)));

__device__ __forceinline__ float rlf(float v, int lane) {
    return __int_as_float(__builtin_amdgcn_readlane(__float_as_int(v), lane));
}
__device__ __forceinline__ unsigned rlu(unsigned v, int lane) {
    return (unsigned)__builtin_amdgcn_readlane((int)v, lane);
}
__device__ __forceinline__ unsigned pack2(float a, float b) {
    half2_t v; v.x = (_Float16)a; v.y = (_Float16)b;   // RNE converts
    return __builtin_bit_cast(unsigned, v);
}
__device__ __forceinline__ half2_t ubc(unsigned u) {
    return __builtin_bit_cast(half2_t, u);
}

// One wave per sequence, grid 1024 = exactly 1 wave/SIMD chip-wide (round-4
// lesson: B=1024 serial chains on 1024 SIMDs admits no other full-chip
// mapping — all gains must come from cycles/step on one wave).
//
// Matvec in f16 packed pairs via v_dot2_f32_f16 (fp32 accumulation):
//   64 fp32 FMAs -> 32 fdot2, 32 readlanes -> 16 readlanes of packed pairs.
// Weights prescaled by -log2e (sigmoid rows) / -2log2e (tanh rows), packed
// f16 once into 32 resident VGPRs (asm-pinned). No per-step LDS reads
// (round-3 lesson: DS pipe is per-CU shared). Gate-select cndmasks dropped
// (round-4-verified: upper half computes bounded garbage, woutv=0 kills it,
// readlanes touch lanes<32 only).
__global__ __launch_bounds__(64, 1) void lstm_dot2_kernel(
    const float* __restrict__ x,      // [B, T]
    const float* __restrict__ W_ih,   // [128]
    const float* __restrict__ W_hh,   // [128, 32]
    const float* __restrict__ b_ih,   // [128]
    const float* __restrict__ b_hh,   // [128]
    const float* __restrict__ W_out,  // [32]
    const float* __restrict__ b_out,  // [1]
    float* __restrict__ out,          // [B, T]
    int T)
{
    __shared__ float psum[64 * 68];   // [step][lane] output partials

    const int b = blockIdx.x;
    const int l = threadIdx.x;        // 0..63
    const int r0 = l;                 // i (l<32) / f (l>=32): sigmoid rows
    const int r1 = l + 64;            // g (l<32) / o (l>=32)
    const bool lo = (l < 32);

    const float sc0 = -LOG2E;                           // sigmoid prescale
    const float sc1 = lo ? (-2.0f * LOG2E) : (-LOG2E);  // tanh / sigmoid

    // Pack prescaled W_hh rows into f16 pairs: 16+16 resident VGPRs.
    unsigned w0u[16], w1u[16];
#pragma unroll
    for (int m = 0; m < 16; ++m) {
        w0u[m] = pack2(W_hh[r0 * 32 + 2 * m] * sc0,
                       W_hh[r0 * 32 + 2 * m + 1] * sc0);
        w1u[m] = pack2(W_hh[r1 * 32 + 2 * m] * sc1,
                       W_hh[r1 * 32 + 2 * m + 1] * sc1);
    }
#pragma unroll
    for (int m = 0; m < 16; ++m)
        asm volatile("" : "+v"(w0u[m]), "+v"(w1u[m]));  // pin; no remat

    const float wih0  = W_ih[r0] * sc0;
    const float wih1  = W_ih[r1] * sc1;
    const float bias0 = (b_ih[r0] + b_hh[r0]) * sc0;
    const float bias1 = (b_ih[r1] + b_hh[r1]) * sc1;
    const float A1 = lo ? 2.0f : 1.0f;   // tanh = 2*rcp(1+e2)-1; sigmoid = rcp(1+e2)
    const float B1 = lo ? -1.0f : 0.0f;
    const float woutv = lo ? W_out[l] : 0.0f;  // upper half garbage -> weight 0
    const float bout  = b_out[0];

    float h = 0.0f, c = 0.0f;
    unsigned hpk = 0u;                // packed f16 pair (h[2m],h[2m+1]) in lane 2m

    const float* xp = x + (size_t)b * T;
    float*       op = out + (size_t)b * T;
    float xv = xp[l];

    for (int t0 = 0; t0 < T; t0 += 64) {
        const int tn = (t0 + 64 < T) ? (t0 + 64) : t0;
        float xv_next = xp[tn + l];   // prefetch next chunk

#pragma unroll 8
        for (int tu = 0; tu < 64; ++tu) {
            const float xt = rlf(xv, tu);

            // Batched broadcast: 16 packed h pairs from even lanes (<32).
            unsigned hp[16];
#pragma unroll
            for (int m = 0; m < 16; ++m)
                hp[m] = rlu(hpk, 2 * m);

            // Gate pre-activations (prescaled), 4 independent dot chains.
            float a0 = fmaf(wih0, xt, bias0);
            float a1 = fmaf(wih1, xt, bias1);
            float b0 = 0.0f, b1 = 0.0f;
#pragma unroll
            for (int m = 0; m < 16; m += 2) {
                a0 = __builtin_amdgcn_fdot2(ubc(w0u[m]),     ubc(hp[m]),     a0, false);
                a1 = __builtin_amdgcn_fdot2(ubc(w1u[m]),     ubc(hp[m]),     a1, false);
                b0 = __builtin_amdgcn_fdot2(ubc(w0u[m + 1]), ubc(hp[m + 1]), b0, false);
                b1 = __builtin_amdgcn_fdot2(ubc(w1u[m + 1]), ubc(hp[m + 1]), b1, false);
            }
            const float G0 = a0 + b0;
            const float G1 = a1 + b1;

            // Activations: exp2 + add + rcp (scale pre-applied to weights).
            const float s0 = __builtin_amdgcn_rcpf(1.0f + __builtin_amdgcn_exp2f(G0));
            const float s1 = fmaf(A1, __builtin_amdgcn_rcpf(
                                 1.0f + __builtin_amdgcn_exp2f(G1)), B1);

            // Exchange across half-wave: lanes<32 get (f,o). No cndmask.
            const float o0 = __shfl_xor(s0, 32, 64);
            const float o1 = __shfl_xor(s1, 32, 64);

            c = fmaf(o0, c, s0 * s1);            // f*c + i*g   (lanes<32)
            const float tc = fmaf(2.0f, __builtin_amdgcn_rcpf(
                1.0f + __builtin_amdgcn_exp2f(-2.0f * LOG2E * c)), -1.0f);
            h = o1 * tc;                         // o * tanh(c) (lanes<32)

            // Repack h for next step's broadcast: lane 2m -> (h[2m], h[2m+1]).
            const float hn = __shfl_xor(h, 1, 64);
            hpk = pack2(h, hn);

            psum[tu * 68 + l] = h * woutv;       // fire-and-forget partial
        }

        __syncthreads();  // single wave: cheap waitcnt; drain psum writes
        const float4* row = (const float4*)(psum + l * 68);
        float4 s4 = row[0];
#pragma unroll
        for (int m = 1; m < 16; ++m) {
            float4 v4 = row[m];
            s4.x += v4.x; s4.y += v4.y; s4.z += v4.z; s4.w += v4.w;
        }
        op[t0 + l] = (s4.x + s4.y) + (s4.z + s4.w) + bout;
        __syncthreads();  // next chunk overwrites psum
        xv = xv_next;
    }
}

extern "C" void kernel_launch(void* const* d_in, const int* in_sizes, int n_in,
                              void* d_out, int out_size, void* d_ws, size_t ws_size,
                              hipStream_t stream) {
    const float* x     = (const float*)d_in[0];   // [1024, 2048, 1]
    const float* W_ih  = (const float*)d_in[1];   // [128, 1]
    const float* W_hh  = (const float*)d_in[2];   // [128, 32]
    const float* b_ih  = (const float*)d_in[3];   // [128]
    const float* b_hh  = (const float*)d_in[4];   // [128]
    const float* W_out = (const float*)d_in[5];   // [1, 32]
    const float* b_out = (const float*)d_in[6];   // [1]
    float* out = (float*)d_out;                   // [1024, 2048, 1]

    const int B = 1024;
    const int T = 2048;
    lstm_dot2_kernel<<<B, 64, 0, stream>>>(x, W_ih, W_hh, b_ih, b_hh,
                                           W_out, b_out, out, T);
}

// Round 9
// 448.957 us; speedup vs baseline: 1.9729x; 1.1709x over previous
//
#include <hip/hip_runtime.h>

#define LOG2E 1.44269504088896340736f

typedef _Float16 half2_t __attribute__((ext_vector_type(2)));

__device__ __forceinline__ float rlf(float v, int lane) {
    return __int_as_float(__builtin_amdgcn_readlane(__float_as_int(v), lane));
}
__device__ __forceinline__ unsigned rlu(unsigned v, int lane) {
    return (unsigned)__builtin_amdgcn_readlane((int)v, lane);
}
__device__ __forceinline__ unsigned pack2(float a, float b) {
    half2_t v; v.x = (_Float16)a; v.y = (_Float16)b;   // RNE (setup only)
    return __builtin_bit_cast(unsigned, v);
}
__device__ __forceinline__ half2_t ubc(unsigned u) {
    return __builtin_bit_cast(half2_t, u);
}

// Cross-half partner (lane^32) on the VALU pipe.
// Rounds 6/7 showed raw inline-asm permlane is a minefield (operand-role
// ambiguity + missing cross-lane hazard wait-states the compiler only
// inserts for intrinsics). The builtin returns BOTH post-swap registers as a
// uint2 vector; under either operand convention each lane's two elements are
// exactly {own, partner}, so r[0]^r[1]^own == partner bit-exactly in every
// lane — semantics-proof and hazard-safe. (Round-8 fix: vector indexing
// r[0]/r[1], not .x/.y.)
__device__ __forceinline__ float swap_half(float v) {
#if __has_builtin(__builtin_amdgcn_permlane32_swap)
    const unsigned u = __builtin_bit_cast(unsigned, v);
    auto r = __builtin_amdgcn_permlane32_swap(u, u, false, false);
    return __builtin_bit_cast(float, (unsigned)(r[0] ^ r[1] ^ u));
#else
    return __shfl_xor(v, 32, 64);     // DS fallback (round-5 proven)
#endif
}

// Neighbor (lane^1) via DPP quad_perm [1,0,3,2] — VALU, hazard-handled.
__device__ __forceinline__ float xor1_dpp(float v) {
    return __int_as_float(__builtin_amdgcn_mov_dpp(
        __float_as_int(v), 0xB1, 0xF, 0xF, true));
}

// One wave per sequence, grid 1024 = 1 wave/SIMD chip-wide (round-4 lesson).
// f16-packed matvec via v_dot2_f32_f16 (round-5 win). Step loop is DS-free
// except the fire-and-forget psum write: cross-half exchanges via
// permlane32_swap builtin, h-pair repack via DPP + v_cvt_pkrtz. Cell state
// carried scaled (cs = -2*log2e*c) so tanh(c) needs no multiply before exp2.
// Upper half-wave computes bounded garbage (inputs stay in (0,1)); woutv=0
// kills its psum term; readlanes only touch lanes<32.
__global__ __launch_bounds__(64, 1) void lstm_pl_kernel(
    const float* __restrict__ x,      // [B, T]
    const float* __restrict__ W_ih,   // [128]
    const float* __restrict__ W_hh,   // [128, 32]
    const float* __restrict__ b_ih,   // [128]
    const float* __restrict__ b_hh,   // [128]
    const float* __restrict__ W_out,  // [32]
    const float* __restrict__ b_out,  // [1]
    float* __restrict__ out,          // [B, T]
    int T)
{
    __shared__ float psum[64 * 68];   // [step][lane] output partials

    const int b = blockIdx.x;
    const int l = threadIdx.x;        // 0..63
    const int r0 = l;                 // i (l<32) / f (l>=32): sigmoid rows
    const int r1 = l + 64;            // g (l<32) / o (l>=32)
    const bool lo = (l < 32);

    const float sc0 = -LOG2E;                           // sigmoid prescale
    const float sc1 = lo ? (-2.0f * LOG2E) : (-LOG2E);  // tanh / sigmoid

    // Pack prescaled W_hh rows into f16 pairs: 32 resident VGPRs.
    unsigned w0u[16], w1u[16];
#pragma unroll
    for (int m = 0; m < 16; ++m) {
        w0u[m] = pack2(W_hh[r0 * 32 + 2 * m] * sc0,
                       W_hh[r0 * 32 + 2 * m + 1] * sc0);
        w1u[m] = pack2(W_hh[r1 * 32 + 2 * m] * sc1,
                       W_hh[r1 * 32 + 2 * m + 1] * sc1);
    }
#pragma unroll
    for (int m = 0; m < 16; ++m)
        asm volatile("" : "+v"(w0u[m]), "+v"(w1u[m]));  // pin; no remat

    const float wih0  = W_ih[r0] * sc0;
    const float wih1  = W_ih[r1] * sc1;
    const float bias0 = (b_ih[r0] + b_hh[r0]) * sc0;
    const float bias1 = (b_ih[r1] + b_hh[r1]) * sc1;
    // s1s: lanes<32 -> -2log2e * tanh(g) = fma(-4log2e, rcp, 2log2e);
    //      lanes>=32 -> sigmoid(o) = rcp  (exactly what lower lanes need)
    const float A1s = lo ? (-4.0f * LOG2E) : 1.0f;
    const float B1s = lo ? ( 2.0f * LOG2E) : 0.0f;
    const float woutv = lo ? W_out[l] : 0.0f;  // upper half garbage -> weight 0
    const float bout  = b_out[0];

    float h = 0.0f, cs = 0.0f;        // cs = -2*log2e*c  (scaled cell state)
    unsigned hpk = 0u;                // packed f16 (h[2m],h[2m+1]) in lane 2m

    const float* xp = x + (size_t)b * T;
    float*       op = out + (size_t)b * T;
    float xv = xp[l];

    for (int t0 = 0; t0 < T; t0 += 64) {
        const int tn = (t0 + 64 < T) ? (t0 + 64) : t0;
        float xv_next = xp[tn + l];   // prefetch next chunk

#pragma unroll 8
        for (int tu = 0; tu < 64; ++tu) {
            const float xt = rlf(xv, tu);

            // Batched broadcast: 16 packed h pairs from even lanes (<32).
            unsigned hp[16];
#pragma unroll
            for (int m = 0; m < 16; ++m)
                hp[m] = rlu(hpk, 2 * m);

            // Gate pre-activations (prescaled), 4 independent dot chains.
            float a0 = fmaf(wih0, xt, bias0);
            float a1 = fmaf(wih1, xt, bias1);
            float b0 = 0.0f, b1 = 0.0f;
#pragma unroll
            for (int m = 0; m < 16; m += 2) {
                a0 = __builtin_amdgcn_fdot2(ubc(w0u[m]),     ubc(hp[m]),     a0, false);
                a1 = __builtin_amdgcn_fdot2(ubc(w1u[m]),     ubc(hp[m]),     a1, false);
                b0 = __builtin_amdgcn_fdot2(ubc(w0u[m + 1]), ubc(hp[m + 1]), b0, false);
                b1 = __builtin_amdgcn_fdot2(ubc(w1u[m + 1]), ubc(hp[m + 1]), b1, false);
            }
            const float G0 = a0 + b0;
            const float G1 = a1 + b1;

            // s0 = sigmoid(i|f); s1s = -2log2e*tanh(g) (lo) | sigmoid(o) (hi)
            const float s0  = __builtin_amdgcn_rcpf(1.0f + __builtin_amdgcn_exp2f(G0));
            const float s1s = fmaf(A1s, __builtin_amdgcn_rcpf(
                                  1.0f + __builtin_amdgcn_exp2f(G1)), B1s);

            // VALU cross-half exchange: lanes<32 get (f, sigmoid(o)).
            const float o0 = swap_half(s0);
            const float o1 = swap_half(s1s);

            // cs = f*cs + i*(-2log2e*g)  -> tanh(c) = 2*rcp(1+exp2(cs)) - 1
            cs = fmaf(o0, cs, s0 * s1s);
            const float tc = fmaf(2.0f, __builtin_amdgcn_rcpf(
                1.0f + __builtin_amdgcn_exp2f(cs)), -1.0f);
            h = o1 * tc;                         // o * tanh(c) (lanes<32)

            // Repack for next step: lane 2m -> (h[2m], h[2m+1]); DPP + pkrtz.
            const float hn = xor1_dpp(h);
            hpk = __builtin_bit_cast(unsigned,
                      __builtin_amdgcn_cvt_pkrtz(h, hn));

            psum[tu * 68 + l] = h * woutv;       // only DS op in the step
        }

        __syncthreads();  // single wave: cheap waitcnt; drain psum writes
        const float4* row = (const float4*)(psum + l * 68);
        float4 s4 = row[0];
#pragma unroll
        for (int m = 1; m < 16; ++m) {
            float4 v4 = row[m];
            s4.x += v4.x; s4.y += v4.y; s4.z += v4.z; s4.w += v4.w;
        }
        op[t0 + l] = (s4.x + s4.y) + (s4.z + s4.w) + bout;
        __syncthreads();  // next chunk overwrites psum
        xv = xv_next;
    }
}

extern "C" void kernel_launch(void* const* d_in, const int* in_sizes, int n_in,
                              void* d_out, int out_size, void* d_ws, size_t ws_size,
                              hipStream_t stream) {
    const float* x     = (const float*)d_in[0];   // [1024, 2048, 1]
    const float* W_ih  = (const float*)d_in[1];   // [128, 1]
    const float* W_hh  = (const float*)d_in[2];   // [128, 32]
    const float* b_ih  = (const float*)d_in[3];   // [128]
    const float* b_hh  = (const float*)d_in[4];   // [128]
    const float* W_out = (const float*)d_in[5];   // [1, 32]
    const float* b_out = (const float*)d_in[6];   // [1]
    float* out = (float*)d_out;                   // [1024, 2048, 1]

    const int B = 1024;
    const int T = 2048;
    lstm_pl_kernel<<<B, 64, 0, stream>>>(x, W_ih, W_hh, b_ih, b_hh,
                                         W_out, b_out, out, T);
}

// Round 10
// 439.883 us; speedup vs baseline: 2.0136x; 1.0206x over previous
//
#include <hip/hip_runtime.h>

#define LOG2E 1.44269504088896340736f

typedef _Float16 half2_t __attribute__((ext_vector_type(2)));

__device__ __forceinline__ float rlf(float v, int lane) {
    return __int_as_float(__builtin_amdgcn_readlane(__float_as_int(v), lane));
}
__device__ __forceinline__ unsigned rlu(unsigned v, int lane) {
    return (unsigned)__builtin_amdgcn_readlane((int)v, lane);
}
__device__ __forceinline__ unsigned pack2(float a, float b) {
    half2_t v; v.x = (_Float16)a; v.y = (_Float16)b;   // RNE (setup only)
    return __builtin_bit_cast(unsigned, v);
}
__device__ __forceinline__ half2_t ubc(unsigned u) {
    return __builtin_bit_cast(half2_t, u);
}

// Cross-half partner (lane^32) on the VALU pipe. The permlane32_swap builtin
// returns both post-swap registers; r[0]^r[1]^own == partner bit-exactly in
// every lane under either operand convention — semantics-proof (round-9
// verified PASS) and hazard-safe. Keep this form; raw-asm/single-register
// variants burned rounds 6-7.
__device__ __forceinline__ float swap_half(float v) {
#if __has_builtin(__builtin_amdgcn_permlane32_swap)
    const unsigned u = __builtin_bit_cast(unsigned, v);
    auto r = __builtin_amdgcn_permlane32_swap(u, u, false, false);
    return __builtin_bit_cast(float, (unsigned)(r[0] ^ r[1] ^ u));
#else
    return __shfl_xor(v, 32, 64);     // DS fallback (round-5 proven)
#endif
}

// Neighbor (lane^1) via DPP quad_perm [1,0,3,2] — VALU, hazard-handled.
__device__ __forceinline__ float xor1_dpp(float v) {
    return __int_as_float(__builtin_amdgcn_mov_dpp(
        __float_as_int(v), 0xB1, 0xF, 0xF, true));
}

// One wave per sequence, grid 1024 = 1 wave/SIMD chip-wide (round-4 lesson:
// occupancy axis is closed). f16-packed matvec via v_dot2_f32_f16 (round-5).
// Step loop is DS-free except one fire-and-forget psum write (round-3
// lesson: DS pipe is per-CU shared). Cross-half exchange via permlane32_swap
// (round-9). Round-10 trims: h = fmaf(2*o1, rcp, -o1) single-FMA tail;
// epilogue reduces only the lower-32 psum entries (upper are exact 0.0 since
// woutv=0 and garbage h is provably finite); unroll 16.
__global__ __launch_bounds__(64, 1) void lstm_pl_kernel(
    const float* __restrict__ x,      // [B, T]
    const float* __restrict__ W_ih,   // [128]
    const float* __restrict__ W_hh,   // [128, 32]
    const float* __restrict__ b_ih,   // [128]
    const float* __restrict__ b_hh,   // [128]
    const float* __restrict__ W_out,  // [32]
    const float* __restrict__ b_out,  // [1]
    float* __restrict__ out,          // [B, T]
    int T)
{
    __shared__ float psum[64 * 68];   // [step][lane] output partials

    const int b = blockIdx.x;
    const int l = threadIdx.x;        // 0..63
    const int r0 = l;                 // i (l<32) / f (l>=32): sigmoid rows
    const int r1 = l + 64;            // g (l<32) / o (l>=32)
    const bool lo = (l < 32);

    const float sc0 = -LOG2E;                           // sigmoid prescale
    const float sc1 = lo ? (-2.0f * LOG2E) : (-LOG2E);  // tanh / sigmoid

    // Pack prescaled W_hh rows into f16 pairs: 32 resident VGPRs.
    unsigned w0u[16], w1u[16];
#pragma unroll
    for (int m = 0; m < 16; ++m) {
        w0u[m] = pack2(W_hh[r0 * 32 + 2 * m] * sc0,
                       W_hh[r0 * 32 + 2 * m + 1] * sc0);
        w1u[m] = pack2(W_hh[r1 * 32 + 2 * m] * sc1,
                       W_hh[r1 * 32 + 2 * m + 1] * sc1);
    }
#pragma unroll
    for (int m = 0; m < 16; ++m)
        asm volatile("" : "+v"(w0u[m]), "+v"(w1u[m]));  // pin; no remat

    const float wih0  = W_ih[r0] * sc0;
    const float wih1  = W_ih[r1] * sc1;
    const float bias0 = (b_ih[r0] + b_hh[r0]) * sc0;
    const float bias1 = (b_ih[r1] + b_hh[r1]) * sc1;
    // s1s: lanes<32 -> -2log2e * tanh(g) = fma(-4log2e, rcp, 2log2e);
    //      lanes>=32 -> sigmoid(o) = rcp  (exactly what lower lanes need)
    const float A1s = lo ? (-4.0f * LOG2E) : 1.0f;
    const float B1s = lo ? ( 2.0f * LOG2E) : 0.0f;
    const float woutv = lo ? W_out[l] : 0.0f;  // upper half garbage -> weight 0
    const float bout  = b_out[0];

    float h = 0.0f, cs = 0.0f;        // cs = -2*log2e*c  (scaled cell state)
    unsigned hpk = 0u;                // packed f16 (h[2m],h[2m+1]) in lane 2m

    const float* xp = x + (size_t)b * T;
    float*       op = out + (size_t)b * T;
    float xv = xp[l];

    for (int t0 = 0; t0 < T; t0 += 64) {
        const int tn = (t0 + 64 < T) ? (t0 + 64) : t0;
        float xv_next = xp[tn + l];   // prefetch next chunk

#pragma unroll 16
        for (int tu = 0; tu < 64; ++tu) {
            const float xt = rlf(xv, tu);

            // Batched broadcast: 16 packed h pairs from even lanes (<32).
            unsigned hp[16];
#pragma unroll
            for (int m = 0; m < 16; ++m)
                hp[m] = rlu(hpk, 2 * m);

            // Gate pre-activations (prescaled), 4 independent dot chains.
            float a0 = fmaf(wih0, xt, bias0);
            float a1 = fmaf(wih1, xt, bias1);
            float b0 = 0.0f, b1 = 0.0f;
#pragma unroll
            for (int m = 0; m < 16; m += 2) {
                a0 = __builtin_amdgcn_fdot2(ubc(w0u[m]),     ubc(hp[m]),     a0, false);
                a1 = __builtin_amdgcn_fdot2(ubc(w1u[m]),     ubc(hp[m]),     a1, false);
                b0 = __builtin_amdgcn_fdot2(ubc(w0u[m + 1]), ubc(hp[m + 1]), b0, false);
                b1 = __builtin_amdgcn_fdot2(ubc(w1u[m + 1]), ubc(hp[m + 1]), b1, false);
            }
            const float G0 = a0 + b0;
            const float G1 = a1 + b1;

            // s0 = sigmoid(i|f); s1s = -2log2e*tanh(g) (lo) | sigmoid(o) (hi)
            const float s0  = __builtin_amdgcn_rcpf(1.0f + __builtin_amdgcn_exp2f(G0));
            const float s1s = fmaf(A1s, __builtin_amdgcn_rcpf(
                                  1.0f + __builtin_amdgcn_exp2f(G1)), B1s);

            // VALU cross-half exchange: lanes<32 get (f, sigmoid(o)).
            const float o0 = swap_half(s0);
            const float o1 = swap_half(s1s);
            const float to1 = o1 + o1;           // early, off critical path

            // cs = f*cs + i*(-2log2e*g); h = o1*tanh(c) = 2*o1*rcp - o1
            cs = fmaf(o0, cs, s0 * s1s);
            const float rc = __builtin_amdgcn_rcpf(
                1.0f + __builtin_amdgcn_exp2f(cs));
            h = fmaf(to1, rc, -o1);              // single-FMA tail (round-10)

            // Repack for next step: lane 2m -> (h[2m], h[2m+1]); DPP + pkrtz.
            const float hn = xor1_dpp(h);
            hpk = __builtin_bit_cast(unsigned,
                      __builtin_amdgcn_cvt_pkrtz(h, hn));

            psum[tu * 68 + l] = h * woutv;       // only DS op in the step
        }

        __syncthreads();  // single wave: cheap waitcnt; drain psum writes
        // Entries 32..63 of each row are exactly 0 (woutv=0) -> reduce m<8.
        const float4* row = (const float4*)(psum + l * 68);
        float4 s4 = row[0];
#pragma unroll
        for (int m = 1; m < 8; ++m) {
            float4 v4 = row[m];
            s4.x += v4.x; s4.y += v4.y; s4.z += v4.z; s4.w += v4.w;
        }
        op[t0 + l] = (s4.x + s4.y) + (s4.z + s4.w) + bout;
        __syncthreads();  // next chunk overwrites psum
        xv = xv_next;
    }
}

extern "C" void kernel_launch(void* const* d_in, const int* in_sizes, int n_in,
                              void* d_out, int out_size, void* d_ws, size_t ws_size,
                              hipStream_t stream) {
    const float* x     = (const float*)d_in[0];   // [1024, 2048, 1]
    const float* W_ih  = (const float*)d_in[1];   // [128, 1]
    const float* W_hh  = (const float*)d_in[2];   // [128, 32]
    const float* b_ih  = (const float*)d_in[3];   // [128]
    const float* b_hh  = (const float*)d_in[4];   // [128]
    const float* W_out = (const float*)d_in[5];   // [1, 32]
    const float* b_out = (const float*)d_in[6];   // [1]
    float* out = (float*)d_out;                   // [1024, 2048, 1]

    const int B = 1024;
    const int T = 2048;
    lstm_pl_kernel<<<B, 64, 0, stream>>>(x, W_ih, W_hh, b_ih, b_hh,
                                         W_out, b_out, out, T);
}